// Round 14
// baseline (140.566 us; speedup 1.0000x reference)
//
#include <hip/hip_runtime.h>
#include <stdint.h>

typedef int i32x4  __attribute__((ext_vector_type(4)));
typedef int i32x16 __attribute__((ext_vector_type(16)));

static constexpr int Mdim   = 16384;     // B*S = 8*2048
static constexpr int Kdim   = 2048;      // D_IN
static constexpr int Ndim   = 2048;      // D_OUT
static constexpr int WELEMS = Ndim * Kdim;   // 4194304

// Fragment-major pack layout (shared by packers and GEMM):
//   chunk(R, c) = 1024 B at base + (R*64 + c)*1024
//   byte l*16 + b of a chunk holds row R*32 + (l&31), k = c*32 + (l>>5)*16 + b

// ---------------- async global->LDS (16B per lane, lane-ordered dest) -------
__device__ __forceinline__ void gload_lds16(const void* g, void* l) {
  __builtin_amdgcn_global_load_lds(
      (const __attribute__((address_space(1))) void*)g,
      (__attribute__((address_space(3))) void*)l,
      16, 0, 0);
}

// ---------------- K1: partial sums of |w| -----------------------------------
__global__ void k_abs_part(const float* __restrict__ w, float* __restrict__ part) {
  const float4* w4 = (const float4*)w;
  float s = 0.f;
  int idx = blockIdx.x * 256 + threadIdx.x;
  #pragma unroll 4
  for (int i = idx; i < WELEMS / 4; i += 256 * 256) {
    float4 v = w4[i];
    s += fabsf(v.x) + fabsf(v.y) + fabsf(v.z) + fabsf(v.w);
  }
  #pragma unroll
  for (int off = 32; off > 0; off >>= 1) s += __shfl_down(s, off);
  __shared__ float sm[4];
  if ((threadIdx.x & 63) == 0) sm[threadIdx.x >> 6] = s;
  __syncthreads();
  if (threadIdx.x == 0) part[blockIdx.x] = sm[0] + sm[1] + sm[2] + sm[3];
}

// ---------------- K2: finalize scale = mean(|w|) ----------------------------
__global__ void k_abs_final(const float* __restrict__ part, float* __restrict__ scal) {
  float s = part[threadIdx.x];           // exactly 256 partials, block = 256
  #pragma unroll
  for (int off = 32; off > 0; off >>= 1) s += __shfl_down(s, off);
  __shared__ float sm[4];
  if ((threadIdx.x & 63) == 0) sm[threadIdx.x >> 6] = s;
  __syncthreads();
  if (threadIdx.x == 0) scal[0] = (sm[0] + sm[1] + sm[2] + sm[3]) / (float)WELEMS;
}

__device__ __forceinline__ int quant4(float4 v, float sc) {
  int a = (int)rintf(v.x / sc); a = a < -128 ? -128 : (a > 127 ? 127 : a);
  int b = (int)rintf(v.y / sc); b = b < -128 ? -128 : (b > 127 ? 127 : b);
  int c = (int)rintf(v.z / sc); c = c < -128 ? -128 : (c > 127 ? 127 : c);
  int d = (int)rintf(v.w / sc); d = d < -128 ? -128 : (d > 127 ? 127 : d);
  return (a & 255) | ((b & 255) << 8) | ((c & 255) << 16) | ((d & 255) << 24);
}

__device__ __forceinline__ int tern4(float4 v, float s) {
  int a = (int)rintf(v.x / s); a = a < -1 ? -1 : (a > 1 ? 1 : a);
  int b = (int)rintf(v.y / s); b = b < -1 ? -1 : (b > 1 ? 1 : b);
  int c = (int)rintf(v.z / s); c = c < -1 ? -1 : (c > 1 ? 1 : c);
  int d = (int)rintf(v.w / s); d = d < -1 ? -1 : (d > 1 ? 1 : d);
  return (a & 255) | ((b & 255) << 8) | ((c & 255) << 16) | ((d & 255) << 24);
}

// LDS row stride for the transpose buffers: 2052 B (513 dwords, odd ->
// bank = (l*513 + k)%32 spreads 32 rows over all 32 banks; <=2-way = free).
static constexpr int LSTR = 2052;

// ---------------- K3: ternary weight quantize + fragment-major pack ---------
__global__ __launch_bounds__(512) void k_wquant(const float* __restrict__ w,
                                                char* __restrict__ wq,
                                                const float* __restrict__ scal) {
  __shared__ char sq[32 * LSTR];
  const float s  = scal[0] + 1e-8f;
  const int   Rg = blockIdx.x;
  const int   wv = threadIdx.x >> 6;     // 0..7
  const int   l  = threadIdx.x & 63;

  #pragma unroll
  for (int it = 0; it < 4; ++it) {
    const int rs = it * 8 + wv;          // row slot 0..31
    const float4* wr = (const float4*)(w + (size_t)(Rg * 32 + rs) * Kdim);
    #pragma unroll
    for (int c = 0; c < 8; ++c)
      *(int*)(&sq[rs * LSTR + (c * 64 + l) * 4]) = tern4(wr[c * 64 + l], s);
  }
  __syncthreads();
  char* dst = wq + (size_t)Rg * 65536;
  #pragma unroll
  for (int i = 0; i < 8; ++i) {
    const int c = i * 8 + wv;            // chunk 0..63
    int p[4];
    #pragma unroll
    for (int j = 0; j < 4; ++j)
      p[j] = *(const int*)(&sq[(l & 31) * LSTR + c * 32 + (l >> 5) * 16 + j * 4]);
    *(int4*)(dst + c * 1024 + l * 16) = make_int4(p[0], p[1], p[2], p[3]);
  }
}

// ---------------- K4: per-row absmax + int8 quantize + pack -----------------
__global__ __launch_bounds__(512) void k_xquant(const float* __restrict__ x,
                                                char* __restrict__ xq,
                                                float* __restrict__ xs) {
  __shared__ char sq[32 * LSTR];
  const int Rg = blockIdx.x;
  const int wv = threadIdx.x >> 6;       // 0..7
  const int l  = threadIdx.x & 63;

  #pragma unroll
  for (int it = 0; it < 4; ++it) {
    const int rs  = it * 8 + wv;
    const int row = Rg * 32 + rs;
    const float4* xr = (const float4*)(x + (size_t)row * Kdim);
    float4 v[8];
    float  m = 0.f;
    #pragma unroll
    for (int c = 0; c < 8; ++c) {
      v[c] = xr[c * 64 + l];
      m = fmaxf(m, fmaxf(fmaxf(fabsf(v[c].x), fabsf(v[c].y)),
                         fmaxf(fabsf(v[c].z), fabsf(v[c].w))));
    }
    #pragma unroll
    for (int off = 1; off < 64; off <<= 1) m = fmaxf(m, __shfl_xor(m, off));
    m = fmaxf(m, 1e-8f);
    const float sc = m / 127.0f;
    if (l == 0) xs[row] = sc;
    #pragma unroll
    for (int c = 0; c < 8; ++c)
      *(int*)(&sq[rs * LSTR + (c * 64 + l) * 4]) = quant4(v[c], sc);
  }
  __syncthreads();
  char* dst = xq + (size_t)Rg * 65536;
  #pragma unroll
  for (int i = 0; i < 8; ++i) {
    const int c = i * 8 + wv;
    int p[4];
    #pragma unroll
    for (int j = 0; j < 4; ++j)
      p[j] = *(const int*)(&sq[(l & 31) * LSTR + c * 32 + (l >> 5) * 16 + j * 4]);
    *(int4*)(dst + c * 1024 + l * 16) = make_int4(p[0], p[1], p[2], p[3]);
  }
}

// ---------------- K5: int8 MFMA GEMM, 256x256, BK=64 ------------------------
// A via LDS ring-4 (4-way wave reuse justifies staging); B DIRECT global->reg
// (wq = 4 MB, L2-resident; per-lane frag = contiguous 16 B of a packed chunk).
// Removes B's DMA-writes and ds_reads: LDS traffic 128 -> 80 KB/tile.
// ONE barrier per K-tile: stage targets buf[(t+2)&3], whose tile-(t-2) reads
// are provably drained (every wave consumed them via MFMA before passing
// barrier t-1).  vmcnt(6) uniform (B(t) 4 + A(t+1) 2 outstanding), never 0
// until the peeled last tile.  B regs double-buffered with static names.
__global__ __launch_bounds__(512, 2) void k_gemm(
    const char* __restrict__ xq, const char* __restrict__ wq,
    const float* __restrict__ xs, const float* __restrict__ scal,
    const float* __restrict__ bias, float* __restrict__ out) {
  __shared__ __attribute__((aligned(128))) char lds[4][16384];

  // XCD-aware bijective swizzle: 512 blocks, 512 % 8 == 0.
  const int hw  = blockIdx.x;
  const int lin = (hw & 7) * 64 + (hw >> 3);
  const int bm  = lin >> 3;               // 64 M-tiles
  const int bn  = lin & 7;                // 8 N-tiles

  const int tid = threadIdx.x;
  const int w   = tid >> 6;               // wave 0..7
  const int l   = tid & 63;
  const int wr  = w >> 2, wc = w & 3;     // 2 x 4 wave grid
  const int l16 = l * 16;

  const char* gA  = xq + (size_t)(bm * 8 + w) * 65536 + l16;           // stage rg=w
  const char* gBf = wq + (size_t)(bn * 8 + wc * 2) * 65536 + l16;      // direct B
  const int   w2k = w * 2048;

#define STAGE_A(t_)                                                       \
  { char* sb = &lds[(t_) & 3][0]; const int kb_ = (t_) * 2048;            \
    gload_lds16(gA + kb_,        sb + w2k);                               \
    gload_lds16(gA + kb_ + 1024, sb + w2k + 1024); }

#define BLOAD(DST, t_)                                                    \
  _Pragma("unroll") for (int ni = 0; ni < 2; ++ni)                        \
    _Pragma("unroll") for (int ks = 0; ks < 2; ++ks)                      \
      DST[ni][ks] = *(const i32x4*)(gBf + (size_t)ni * 65536 + ((t_) * 2 + ks) * 1024);

  i32x16 acc[4][2] = {};
  i32x4  bC[2][2], bN[2][2];

  STAGE_A(0); STAGE_A(1);                 // 4 A-gloads in flight
  BLOAD(bC, 0);                           // B for tile 0

#define TILE(T_, BCU, BNX, VMTOK, DOB, DOSTG)                               \
  {                                                                         \
    VMTOK                                                                   \
    __builtin_amdgcn_s_barrier();                                           \
    asm volatile("" ::: "memory");                                          \
    const char* base_ = &lds[(T_) & 3][0];                                  \
    i32x4 aF[4][2];                                                         \
    _Pragma("unroll") for (int mi = 0; mi < 4; ++mi)                        \
      _Pragma("unroll") for (int ks = 0; ks < 2; ++ks)                      \
        aF[mi][ks] = *(const i32x4*)(base_ + ((wr*4+mi)*2+ks)*1024 + l16);  \
    if (DOB) BLOAD(BNX, (T_) + 1)                                           \
    if (DOSTG) STAGE_A((T_) + 2)                                            \
    __builtin_amdgcn_s_setprio(1);                                          \
    _Pragma("unroll") for (int ks = 0; ks < 2; ++ks)                        \
      _Pragma("unroll") for (int mi = 0; mi < 4; ++mi)                      \
        _Pragma("unroll") for (int ni = 0; ni < 2; ++ni)                    \
          acc[mi][ni] = __builtin_amdgcn_mfma_i32_32x32x32_i8(              \
              aF[mi][ks], BCU[ni][ks], acc[mi][ni], 0, 0, 0);               \
    __builtin_amdgcn_s_setprio(0);                                          \
  }

#define VM6  asm volatile("s_waitcnt vmcnt(6)" ::: "memory");
#define VM4  asm volatile("s_waitcnt vmcnt(4)" ::: "memory");

  for (int t = 0; t < 30; t += 2) {       // tiles 0..29: uniform regime
    TILE(t,     bC, bN, VM6, 1, 1);
    TILE(t + 1, bN, bC, VM6, 1, 1);
  }
  TILE(30, bC, bN, VM6, 1, 0);            // loads B(31); no stage (A done)
  TILE(31, bN, bC, VM4, 0, 0);            // A(31): only B(31)'s 4 newer loads
#undef TILE
#undef STAGE_A
#undef BLOAD
#undef VM6
#undef VM4

  // epilogue: C/D mapping col = lane&31, row = (r&3) + 8*(r>>2) + 4*(lane>>5)
  const float wsc = scal[0];
  const int   lhi = (l >> 5) * 4, lcol = l & 31;
  float bc[2];
  #pragma unroll
  for (int ni = 0; ni < 2; ++ni)
    bc[ni] = bias[bn * 256 + wc * 64 + ni * 32 + lcol];

  #pragma unroll
  for (int mi = 0; mi < 4; ++mi) {
    const int rb = bm * 256 + wr * 128 + mi * 32 + lhi;
    #pragma unroll
    for (int r = 0; r < 16; ++r) {
      const int   row = rb + (r & 3) + 8 * (r >> 2);
      const float sv  = wsc * xs[row];
      #pragma unroll
      for (int ni = 0; ni < 2; ++ni) {
        const int col = bn * 256 + wc * 64 + ni * 32 + lcol;
        out[(size_t)row * Ndim + col] = (float)acc[mi][ni][r] * sv + bc[ni];
      }
    }
  }
}

// ---------------- launch -----------------------------------------------------
extern "C" void kernel_launch(void* const* d_in, const int* in_sizes, int n_in,
                              void* d_out, int out_size, void* d_ws, size_t ws_size,
                              hipStream_t stream) {
  const float* x    = (const float*)d_in[0];
  const float* wgt  = (const float*)d_in[1];
  const float* bias = (const float*)d_in[2];
  float* out = (float*)d_out;

  float* ws_f = (float*)d_ws;
  float* scal = ws_f;               // 1 float
  float* part = ws_f + 64;          // 256 floats
  float* xs   = ws_f + 1024;        // 16384 floats
  char*  wq   = (char*)(ws_f + 20480);          // 4 MiB packed, 16B-aligned
  char*  xq   = wq + (size_t)WELEMS;            // 32 MiB packed, 16B-aligned

  hipLaunchKernelGGL(k_abs_part,  dim3(256),      dim3(256), 0, stream, wgt, part);
  hipLaunchKernelGGL(k_abs_final, dim3(1),        dim3(256), 0, stream, part, scal);
  hipLaunchKernelGGL(k_wquant,    dim3(64),       dim3(512), 0, stream, wgt, wq, scal);
  hipLaunchKernelGGL(k_xquant,    dim3(Mdim/32),  dim3(512), 0, stream, x, xq, xs);
  hipLaunchKernelGGL(k_gemm,      dim3((Mdim/256)*(Ndim/256)), dim3(512), 0, stream,
                     xq, wq, xs, scal, bias, out);
}

// Round 17
// 138.699 us; speedup vs baseline: 1.0135x; 1.0135x over previous
//
#include <hip/hip_runtime.h>
#include <stdint.h>

typedef int i32x4  __attribute__((ext_vector_type(4)));
typedef int i32x16 __attribute__((ext_vector_type(16)));

static constexpr int Mdim   = 16384;     // B*S = 8*2048
static constexpr int Kdim   = 2048;      // D_IN
static constexpr int Ndim   = 2048;      // D_OUT
static constexpr int WELEMS = Ndim * Kdim;   // 4194304

// Fragment-major pack layout (shared by packers and GEMM):
//   chunk(R, c) = 1024 B at base + (R*64 + c)*1024
//   byte l*16 + b of a chunk holds row R*32 + (l&31), k = c*32 + (l>>5)*16 + b

// ---------------- async global->LDS (16B per lane, lane-ordered dest) -------
__device__ __forceinline__ void gload_lds16(const void* g, void* l) {
  __builtin_amdgcn_global_load_lds(
      (const __attribute__((address_space(1))) void*)g,
      (__attribute__((address_space(3))) void*)l,
      16, 0, 0);
}

// ---------------- K1: partial sums of |w| -----------------------------------
__global__ void k_abs_part(const float* __restrict__ w, float* __restrict__ part) {
  const float4* w4 = (const float4*)w;
  float s = 0.f;
  int idx = blockIdx.x * 256 + threadIdx.x;
  #pragma unroll 4
  for (int i = idx; i < WELEMS / 4; i += 256 * 256) {
    float4 v = w4[i];
    s += fabsf(v.x) + fabsf(v.y) + fabsf(v.z) + fabsf(v.w);
  }
  #pragma unroll
  for (int off = 32; off > 0; off >>= 1) s += __shfl_down(s, off);
  __shared__ float sm[4];
  if ((threadIdx.x & 63) == 0) sm[threadIdx.x >> 6] = s;
  __syncthreads();
  if (threadIdx.x == 0) part[blockIdx.x] = sm[0] + sm[1] + sm[2] + sm[3];
}

// ---------------- K2: finalize scale = mean(|w|) ----------------------------
__global__ void k_abs_final(const float* __restrict__ part, float* __restrict__ scal) {
  float s = part[threadIdx.x];           // exactly 256 partials, block = 256
  #pragma unroll
  for (int off = 32; off > 0; off >>= 1) s += __shfl_down(s, off);
  __shared__ float sm[4];
  if ((threadIdx.x & 63) == 0) sm[threadIdx.x >> 6] = s;
  __syncthreads();
  if (threadIdx.x == 0) scal[0] = (sm[0] + sm[1] + sm[2] + sm[3]) / (float)WELEMS;
}

__device__ __forceinline__ int quant4(float4 v, float sc) {
  int a = (int)rintf(v.x / sc); a = a < -128 ? -128 : (a > 127 ? 127 : a);
  int b = (int)rintf(v.y / sc); b = b < -128 ? -128 : (b > 127 ? 127 : b);
  int c = (int)rintf(v.z / sc); c = c < -128 ? -128 : (c > 127 ? 127 : c);
  int d = (int)rintf(v.w / sc); d = d < -128 ? -128 : (d > 127 ? 127 : d);
  return (a & 255) | ((b & 255) << 8) | ((c & 255) << 16) | ((d & 255) << 24);
}

__device__ __forceinline__ int tern4(float4 v, float s) {
  int a = (int)rintf(v.x / s); a = a < -1 ? -1 : (a > 1 ? 1 : a);
  int b = (int)rintf(v.y / s); b = b < -1 ? -1 : (b > 1 ? 1 : b);
  int c = (int)rintf(v.z / s); c = c < -1 ? -1 : (c > 1 ? 1 : c);
  int d = (int)rintf(v.w / s); d = d < -1 ? -1 : (d > 1 ? 1 : d);
  return (a & 255) | ((b & 255) << 8) | ((c & 255) << 16) | ((d & 255) << 24);
}

// LDS row stride for the transpose buffers: 2052 B (513 dwords, odd ->
// bank = (l*513 + k)%32 spreads 32 rows over all 32 banks; <=2-way = free).
static constexpr int LSTR = 2052;

// ---------------- K3: ternary weight quantize + fragment-major pack ---------
__global__ __launch_bounds__(512) void k_wquant(const float* __restrict__ w,
                                                char* __restrict__ wq,
                                                const float* __restrict__ scal) {
  __shared__ char sq[32 * LSTR];
  const float s  = scal[0] + 1e-8f;
  const int   Rg = blockIdx.x;
  const int   wv = threadIdx.x >> 6;     // 0..7
  const int   l  = threadIdx.x & 63;

  #pragma unroll
  for (int it = 0; it < 4; ++it) {
    const int rs = it * 8 + wv;          // row slot 0..31
    const float4* wr = (const float4*)(w + (size_t)(Rg * 32 + rs) * Kdim);
    #pragma unroll
    for (int c = 0; c < 8; ++c)
      *(int*)(&sq[rs * LSTR + (c * 64 + l) * 4]) = tern4(wr[c * 64 + l], s);
  }
  __syncthreads();
  char* dst = wq + (size_t)Rg * 65536;
  #pragma unroll
  for (int i = 0; i < 8; ++i) {
    const int c = i * 8 + wv;            // chunk 0..63
    int p[4];
    #pragma unroll
    for (int j = 0; j < 4; ++j)
      p[j] = *(const int*)(&sq[(l & 31) * LSTR + c * 32 + (l >> 5) * 16 + j * 4]);
    *(int4*)(dst + c * 1024 + l * 16) = make_int4(p[0], p[1], p[2], p[3]);
  }
}

// ---------------- K4: per-row absmax + int8 quantize + pack -----------------
__global__ __launch_bounds__(512) void k_xquant(const float* __restrict__ x,
                                                char* __restrict__ xq,
                                                float* __restrict__ xs) {
  __shared__ char sq[32 * LSTR];
  const int Rg = blockIdx.x;
  const int wv = threadIdx.x >> 6;       // 0..7
  const int l  = threadIdx.x & 63;

  #pragma unroll
  for (int it = 0; it < 4; ++it) {
    const int rs  = it * 8 + wv;
    const int row = Rg * 32 + rs;
    const float4* xr = (const float4*)(x + (size_t)row * Kdim);
    float4 v[8];
    float  m = 0.f;
    #pragma unroll
    for (int c = 0; c < 8; ++c) {
      v[c] = xr[c * 64 + l];
      m = fmaxf(m, fmaxf(fmaxf(fabsf(v[c].x), fabsf(v[c].y)),
                         fmaxf(fabsf(v[c].z), fabsf(v[c].w))));
    }
    #pragma unroll
    for (int off = 1; off < 64; off <<= 1) m = fmaxf(m, __shfl_xor(m, off));
    m = fmaxf(m, 1e-8f);
    const float sc = m / 127.0f;
    if (l == 0) xs[row] = sc;
    #pragma unroll
    for (int c = 0; c < 8; ++c)
      *(int*)(&sq[rs * LSTR + (c * 64 + l) * 4]) = quant4(v[c], sc);
  }
  __syncthreads();
  char* dst = xq + (size_t)Rg * 65536;
  #pragma unroll
  for (int i = 0; i < 8; ++i) {
    const int c = i * 8 + wv;
    int p[4];
    #pragma unroll
    for (int j = 0; j < 4; ++j)
      p[j] = *(const int*)(&sq[(l & 31) * LSTR + c * 32 + (l >> 5) * 16 + j * 4]);
    *(int4*)(dst + c * 1024 + l * 16) = make_int4(p[0], p[1], p[2], p[3]);
  }
}

// ---------------- K5: int8 MFMA GEMM, 128x128 tile, BK=64, HIGH TLP ---------
// out = (scale*xs[m]) * (xq . wq^T) + bias
// 256 threads = 4 waves (2x2), wave tile 64x64 = acc[2][2] of 32x32 mfma.
// Ring-2 LDS = 32 KiB + launch_bounds(256,4) (VGPR<=128) -> FOUR co-resident
// blocks per CU = 4 independent barrier domains per SIMD.  One block's
// vmcnt/barrier stall is covered by the other blocks' MFMA (m114 overlap) --
// the single-barrier-domain invariant shared by all six prior nulls.
// Per tile: {vmcnt(4); bar; ds_read 8 x b128; bar; STAGE(t+2); setprio MFMA}.
// vmcnt(4) confirms tile t (t+1's 4 per-wave loads stay in flight); never 0
// until the peeled tail.
__global__ __launch_bounds__(256, 4) void k_gemm(
    const char* __restrict__ xq, const char* __restrict__ wq,
    const float* __restrict__ xs, const float* __restrict__ scal,
    const float* __restrict__ bias, float* __restrict__ out) {
  __shared__ __attribute__((aligned(128))) char lds[2][16384];

  // XCD-aware bijective swizzle: 2048 blocks, 2048 % 8 == 0.
  // Per XCD: 16 contiguous bm-panels x all bn -> A panels L2-local.
  const int hw  = blockIdx.x;
  const int lin = (hw & 7) * 256 + (hw >> 3);
  const int bm  = lin >> 4;               // 128 M-tiles
  const int bn  = lin & 15;               // 16 N-tiles

  const int tid = threadIdx.x;
  const int w   = tid >> 6;               // wave 0..3
  const int l   = tid & 63;
  const int wr  = w >> 1, wc = w & 1;     // 2 x 2 wave grid
  const int l16 = l * 16;

  // staging: wave w stages R-group w of A (rows w*32..) and of B
  const char* gA = xq + (size_t)(bm * 4 + w) * 65536 + l16;
  const char* gB = wq + (size_t)(bn * 4 + w) * 65536 + l16;
  const int   w2k = w * 2048;

#define STAGE(t_)                                                         \
  { char* sb = &lds[(t_) & 1][0]; const int kb_ = (t_) * 2048;            \
    gload_lds16(gA + kb_,        sb + w2k);                               \
    gload_lds16(gA + kb_ + 1024, sb + w2k + 1024);                        \
    gload_lds16(gB + kb_,        sb + 8192 + w2k);                        \
    gload_lds16(gB + kb_ + 1024, sb + 8192 + w2k + 1024); }

  i32x16 acc[2][2] = {};

  STAGE(0); STAGE(1);                     // 8 per-wave loads in flight

#define TILE(T_, VMTOK, DOSTG)                                              \
  {                                                                         \
    VMTOK                                                                   \
    __builtin_amdgcn_s_barrier();                                           \
    asm volatile("" ::: "memory");                                          \
    const char* base_ = &lds[(T_) & 1][0];                                  \
    i32x4 aF[2][2], bF[2][2];                                               \
    _Pragma("unroll") for (int mi = 0; mi < 2; ++mi)                        \
      _Pragma("unroll") for (int ks = 0; ks < 2; ++ks)                      \
        aF[mi][ks] = *(const i32x4*)(base_ + ((wr*2+mi)*2+ks)*1024 + l16);  \
    _Pragma("unroll") for (int ni = 0; ni < 2; ++ni)                        \
      _Pragma("unroll") for (int ks = 0; ks < 2; ++ks)                      \
        bF[ni][ks] = *(const i32x4*)(base_ + 8192 + ((wc*2+ni)*2+ks)*1024 + l16); \
    __builtin_amdgcn_s_barrier();                                           \
    asm volatile("" ::: "memory");                                          \
    if (DOSTG) STAGE((T_) + 2)                                              \
    __builtin_amdgcn_s_setprio(1);                                          \
    _Pragma("unroll") for (int ks = 0; ks < 2; ++ks)                        \
      _Pragma("unroll") for (int mi = 0; mi < 2; ++mi)                      \
        _Pragma("unroll") for (int ni = 0; ni < 2; ++ni)                    \
          acc[mi][ni] = __builtin_amdgcn_mfma_i32_32x32x32_i8(              \
              aF[mi][ks], bF[ni][ks], acc[mi][ni], 0, 0, 0);                \
    __builtin_amdgcn_s_setprio(0);                                          \
  }

#define VM4  asm volatile("s_waitcnt vmcnt(4)" ::: "memory");
#define VM0  asm volatile("s_waitcnt vmcnt(0)" ::: "memory");

  #pragma unroll 2
  for (int t = 0; t < 30; ++t)            // uniform: confirm t, stage t+2
    TILE(t, VM4, 1)
  TILE(30, VM4, 0)                        // tile 31 stays in flight
  TILE(31, VM0, 0)                        // queue empties (last tile only)
#undef TILE
#undef STAGE
#undef VM4
#undef VM0

  // epilogue: C/D mapping col = lane&31, row = (r&3) + 8*(r>>2) + 4*(lane>>5)
  const float wsc = scal[0];
  const int   lhi = (l >> 5) * 4, lcol = l & 31;
  float bc[2];
  #pragma unroll
  for (int ni = 0; ni < 2; ++ni)
    bc[ni] = bias[bn * 128 + wc * 64 + ni * 32 + lcol];

  #pragma unroll
  for (int mi = 0; mi < 2; ++mi) {
    const int rb = bm * 128 + wr * 64 + mi * 32 + lhi;
    #pragma unroll
    for (int r = 0; r < 16; ++r) {
      const int   row = rb + (r & 3) + 8 * (r >> 2);
      const float sv  = wsc * xs[row];
      #pragma unroll
      for (int ni = 0; ni < 2; ++ni) {
        const int col = bn * 128 + wc * 64 + ni * 32 + lcol;
        out[(size_t)row * Ndim + col] = (float)acc[mi][ni][r] * sv + bc[ni];
      }
    }
  }
}

// ---------------- launch -----------------------------------------------------
extern "C" void kernel_launch(void* const* d_in, const int* in_sizes, int n_in,
                              void* d_out, int out_size, void* d_ws, size_t ws_size,
                              hipStream_t stream) {
  const float* x    = (const float*)d_in[0];
  const float* wgt  = (const float*)d_in[1];
  const float* bias = (const float*)d_in[2];
  float* out = (float*)d_out;

  float* ws_f = (float*)d_ws;
  float* scal = ws_f;               // 1 float
  float* part = ws_f + 64;          // 256 floats
  float* xs   = ws_f + 1024;        // 16384 floats
  char*  wq   = (char*)(ws_f + 20480);          // 4 MiB packed, 16B-aligned
  char*  xq   = wq + (size_t)WELEMS;            // 32 MiB packed, 16B-aligned

  hipLaunchKernelGGL(k_abs_part,  dim3(256),      dim3(256), 0, stream, wgt, part);
  hipLaunchKernelGGL(k_abs_final, dim3(1),        dim3(256), 0, stream, part, scal);
  hipLaunchKernelGGL(k_wquant,    dim3(64),       dim3(512), 0, stream, wgt, wq, scal);
  hipLaunchKernelGGL(k_xquant,    dim3(Mdim/32),  dim3(512), 0, stream, x, xq, xs);
  hipLaunchKernelGGL(k_gemm,      dim3((Mdim/128)*(Ndim/128)), dim3(256), 0, stream,
                     xq, wq, xs, scal, bias, out);
}